// Round 10
// baseline (540.900 us; speedup 1.0000x reference)
//
#include <hip/hip_runtime.h>
#include <stdint.h>

#define NN 4096
#define NCLS 5
#define NWORD 64
#define SCORE_TH 0.05f
#define NMS_TH 0.3f

// monotone f32 -> u32 map (order-preserving, handles sign)
__device__ __forceinline__ uint32_t fmap(float f) {
    uint32_t u = __float_as_uint(f);
    return (u & 0x80000000u) ? ~u : (u | 0x80000000u);
}
__device__ __forceinline__ float funmap(uint32_t m) {
    uint32_t u = (m & 0x80000000u) ? (m & 0x7fffffffu) : ~m;
    return __uint_as_float(u);
}

// K1: softmax + bbox transform + clip. Writes out cols 0..5 and u64 sort keys.
__global__ void k_prep(const float* __restrict__ prop, const float* __restrict__ pred,
                       const float* __restrict__ cls, float* __restrict__ out,
                       uint64_t* __restrict__ skey) {
    int i = blockIdx.x * 256 + threadIdx.x;
    if (i >= NN) return;
    const float* pr = prop + i * 7;
    float l0 = pr[1], l1 = pr[2], l2 = pr[3];
    float h0 = pr[4], h1 = pr[5], h2 = pr[6];
    float s0 = h0 - l0 + 1.f, s1 = h1 - l1 + 1.f, s2 = h2 - l2 + 1.f;
    float c0 = l0 + 0.5f * s0, c1 = l1 + 0.5f * s1, c2 = l2 + 0.5f * s2;

    float sc[6];
    float mx = -3.4e38f;
#pragma unroll
    for (int c = 0; c < 6; ++c) { sc[c] = cls[i * 6 + c]; mx = fmaxf(mx, sc[c]); }
    float sum = 0.f;
#pragma unroll
    for (int c = 0; c < 6; ++c) { sc[c] = expf(sc[c] - mx); sum += sc[c]; }
    float inv = 1.f / sum;

#pragma unroll
    for (int c = 1; c < 6; ++c) {
        const float* d = pred + i * 36 + c * 6;
        float dc0 = d[0] / 10.f, dc1 = d[1] / 10.f, dc2 = d[2] / 10.f;
        float ds0 = d[3] / 5.f, ds1 = d[4] / 5.f, ds2 = d[5] / 5.f;
        float pc0 = dc0 * s0 + c0, pc1 = dc1 * s1 + c1, pc2 = dc2 * s2 + c2;
        float ps0 = expf(ds0) * s0, ps1 = expf(ds1) * s1, ps2 = expf(ds2) * s2;
        float o0 = fminf(fmaxf(pc0 - 0.5f * ps0, 0.f), 1023.f);
        float o1 = fminf(fmaxf(pc1 - 0.5f * ps1, 0.f), 1023.f);
        float o2 = fminf(fmaxf(pc2 - 0.5f * ps2, 0.f), 1023.f);
        float o3 = fminf(fmaxf(pc0 + 0.5f * ps0 - 1.f, 0.f), 1023.f);
        float o4 = fminf(fmaxf(pc1 + 0.5f * ps1 - 1.f, 0.f), 1023.f);
        float o5 = fminf(fmaxf(pc2 + 0.5f * ps2 - 1.f, 0.f), 1023.f);
        float* ob = out + ((size_t)(c - 1) * NN + i) * 7;
        ob[0] = o0; ob[1] = o1; ob[2] = o2; ob[3] = o3; ob[4] = o4; ob[5] = o5;
        float score = sc[c] * inv;
        // key: (mapped score desc, index asc) -> single u64 greater-than compare
        skey[(c - 1) * NN + i] = ((uint64_t)fmap(score) << 12) | (uint32_t)(4095 - i);
    }
}

// K2: O(N^2) counting rank-sort via u64 keys.
__global__ void __launch_bounds__(256) k_sort(const uint64_t* __restrict__ skey,
                                              const float* __restrict__ out,
                                              float* __restrict__ sscores,
                                              unsigned short* __restrict__ order,
                                              float* __restrict__ sboxes) {
    int c = blockIdx.y;
    int i = blockIdx.x * 256 + threadIdx.x;
    const uint64_t* K = skey + c * NN;
    uint64_t ki = K[i];
    int rank = 0;
#pragma unroll 2
    for (int j = 0; j < NN; j += 8) {
        uint64_t k0 = K[j], k1 = K[j + 1], k2 = K[j + 2], k3 = K[j + 3];
        uint64_t k4 = K[j + 4], k5 = K[j + 5], k6 = K[j + 6], k7 = K[j + 7];
        int a = (k0 > ki) + (k1 > ki) + (k2 > ki) + (k3 > ki);
        int b = (k4 > ki) + (k5 > ki) + (k6 > ki) + (k7 > ki);
        rank += a + b;
    }
    int io = c * NN + rank;
    order[io] = (unsigned short)i;
    sscores[io] = funmap((uint32_t)(ki >> 12));
    const float* b = out + ((size_t)c * NN + i) * 7;
    float* sb = sboxes + (size_t)io * 6;
#pragma unroll
    for (int k = 0; k < 6; ++k) sb[k] = b[k];
}

// K3: suppression bitmask, UPPER TRIANGLE ONLY (cb>=rb). 4 waves/block.
__global__ void __launch_bounds__(256) k_mask(const float* __restrict__ sboxes,
                                              uint64_t* __restrict__ mask,
                                              uint64_t* __restrict__ diag) {
    int tid = threadIdx.x;
    int wid = tid >> 6, lane = tid & 63;
    int rb = blockIdx.y, c = blockIdx.z;
    int cb = rb + blockIdx.x * 4 + wid;
    bool active = (cb < 64);

    __shared__ float cB[4][64][6];
    __shared__ float cV[4][64];

    int r = rb * 64 + lane;
    float rl0 = 0, rl1 = 0, rl2 = 0, rh0 = 0, rh1 = 0, rh2 = 0, vi = 0;
    if (active) {
        const float* rp = sboxes + ((size_t)c * NN + r) * 6;
        rl0 = rp[0]; rl1 = rp[1]; rl2 = rp[2];
        rh0 = rp[3]; rh1 = rp[4]; rh2 = rp[5];
        vi = (rh0 - rl0 + 1.f) * (rh1 - rl1 + 1.f) * (rh2 - rl2 + 1.f);
        const float* cp = sboxes + ((size_t)c * NN + cb * 64 + lane) * 6;
#pragma unroll
        for (int k = 0; k < 6; ++k) cB[wid][lane][k] = cp[k];
        cV[wid][lane] = (cB[wid][lane][3] - cB[wid][lane][0] + 1.f) *
                        (cB[wid][lane][4] - cB[wid][lane][1] + 1.f) *
                        (cB[wid][lane][5] - cB[wid][lane][2] + 1.f);
    }
    __syncthreads();
    if (!active) return;

    uint64_t bits = 0;
    for (int j2 = 0; j2 < 64; ++j2) {
        int j = cb * 64 + j2;
        if (j > r) {
            float w0 = fmaxf(fminf(rh0, cB[wid][j2][3]) - fmaxf(rl0, cB[wid][j2][0]) + 1.f, 0.f);
            float w1 = fmaxf(fminf(rh1, cB[wid][j2][4]) - fmaxf(rl1, cB[wid][j2][1]) + 1.f, 0.f);
            float w2 = fmaxf(fminf(rh2, cB[wid][j2][5]) - fmaxf(rl2, cB[wid][j2][2]) + 1.f, 0.f);
            float inter = w0 * w1 * w2;
            float iou = inter / (vi + cV[wid][j2] - inter);
            if (iou > NMS_TH) bits |= 1ull << j2;
        }
    }
    mask[((size_t)c * NN + r) * NWORD + cb] = bits;
    if (cb == rb) diag[(size_t)c * NN + r] = bits;
}

// K4: sequential greedy reduce, one wave per class.
// Staging: reg-staged deep-pipelined loads (32x global_load_dwordx4 in flight
// -> ds_write_b128 double buffer). R5/R6 evidence: a single wave's
// global_load_lds stream pipelines to depth ~2 only (~4.7 B/cy); plain vector
// loads pipeline to depth 32 (~65 B/cy at ~500cy L3 latency).
// Chain: register-only (readlane), sub-blocked 16-wide so the VALU readlanes
// of the next sub-block overlap the SALU chain of the current one.
__global__ void __launch_bounds__(64, 1) k_nms(const float* __restrict__ sscores,
                                               const unsigned short* __restrict__ order,
                                               const uint64_t* __restrict__ mask,
                                               const uint64_t* __restrict__ diag,
                                               float* __restrict__ kept) {
    __shared__ __align__(16) uint64_t ltile[2][64 * 64];  // 2 x 32KB
    __shared__ __align__(16) uint64_t ldiag[NN];          // 32KB
    __shared__ uint64_t sh[64];

    int c = blockIdx.x;
    int lane = threadIdx.x;
    const uint64_t* M = mask + (size_t)c * NN * NWORD;
    const uint64_t* D = diag + (size_t)c * NN;
    const float* ss = sscores + c * NN;

    uint4 rg[32];  // 128 VGPRs of staging registers, statically indexed

    // ---- prologue ----
    // stage ldiag (32KB): 32 deep-pipelined loads -> LDS
    {
        const uint4* g = (const uint4*)D;
#pragma unroll
        for (int i = 0; i < 32; ++i) rg[i] = g[i * 64 + lane];
        uint4* l = (uint4*)ldiag;
#pragma unroll
        for (int i = 0; i < 32; ++i) l[i * 64 + lane] = rg[i];
    }
    // stage tile 0
    {
        const uint4* g = (const uint4*)M;
#pragma unroll
        for (int i = 0; i < 32; ++i) rg[i] = g[i * 64 + lane];
        uint4* l = (uint4*)ltile[0];
#pragma unroll
        for (int i = 0; i < 32; ++i) l[i * 64 + lane] = rg[i];
    }
    // issue tile 1 loads (land during round 0)
    {
        const uint4* g = (const uint4*)(M + (1ull << 12));
#pragma unroll
        for (int i = 0; i < 32; ++i) rg[i] = g[i * 64 + lane];
    }
    __builtin_amdgcn_sched_barrier(0);

    // init remv: lane l owns word l = indices l*64..l*64+63; bit j = !(score>TH)
    uint64_t remv = 0;
    {
        const float4* sl = (const float4*)(ss + lane * 64);
#pragma unroll
        for (int q = 0; q < 16; ++q) {
            float4 v = sl[q];
            if (!(v.x > SCORE_TH)) remv |= 1ull << (q * 4);
            if (!(v.y > SCORE_TH)) remv |= 1ull << (q * 4 + 1);
            if (!(v.z > SCORE_TH)) remv |= 1ull << (q * 4 + 2);
            if (!(v.w > SCORE_TH)) remv |= 1ull << (q * 4 + 3);
        }
    }

    int cur = 0;
#pragma unroll 1
    for (int w = 0; w < 64; ++w) {
        // write staged tile w+1 (regs have had a full round to land; the
        // compiler emits counted vmcnt waits per rg[i] use)
        if (w < 63) {
            uint4* l = (uint4*)ltile[cur ^ 1];
#pragma unroll
            for (int i = 0; i < 32; ++i) l[i * 64 + lane] = rg[i];
        }
        // issue loads for tile w+2 (in flight across the whole next round)
        if (w < 62) {
            const uint4* g = (const uint4*)(M + ((size_t)(w + 2) << 12));
#pragma unroll
            for (int i = 0; i < 32; ++i) rg[i] = g[i * 64 + lane];
        }
        __builtin_amdgcn_sched_barrier(0);

        // --- phase 1: register-only serial keep-chain, sub-blocked ---
        uint32_t rlo = __builtin_amdgcn_readlane((uint32_t)remv, w);
        uint32_t rhi = __builtin_amdgcn_readlane((uint32_t)(remv >> 32), w);
        uint64_t rw = ((uint64_t)rhi << 32) | rlo;
        uint64_t mydg = ldiag[(w << 6) | lane];  // one lane-distributed ds_read
        uint32_t dgl = (uint32_t)mydg, dgh = (uint32_t)(mydg >> 32);
        uint64_t kmask = 0;
#pragma unroll
        for (int sb = 0; sb < 4; ++sb) {
            uint32_t lo[16], hi[16];
#pragma unroll
            for (int b = 0; b < 16; ++b) {
                lo[b] = __builtin_amdgcn_readlane(dgl, sb * 16 + b);
                hi[b] = __builtin_amdgcn_readlane(dgh, sb * 16 + b);
            }
#pragma unroll
            for (int b = 0; b < 16; ++b) {
                int bb = sb * 16 + b;
                if (!((rw >> bb) & 1)) {
                    rw |= ((uint64_t)hi[b] << 32) | lo[b];
                    kmask |= 1ull << bb;
                }
            }
        }

        // --- phase 2: parallel tile ORs, gated by uniform kmask bits ---
        const uint64_t* T = ltile[cur];
        uint64_t a0 = 0, a1 = 0, a2 = 0, a3 = 0;
#pragma unroll
        for (int b = 0; b < 64; b += 4) {
            uint64_t m0 = T[((b + 0) << 6) | lane];
            uint64_t m1 = T[((b + 1) << 6) | lane];
            uint64_t m2 = T[((b + 2) << 6) | lane];
            uint64_t m3 = T[((b + 3) << 6) | lane];
            uint64_t k0 = 0ull - ((kmask >> (b + 0)) & 1ull);
            uint64_t k1 = 0ull - ((kmask >> (b + 1)) & 1ull);
            uint64_t k2 = 0ull - ((kmask >> (b + 2)) & 1ull);
            uint64_t k3 = 0ull - ((kmask >> (b + 3)) & 1ull);
            a0 |= m0 & k0;
            a1 |= m1 & k1;
            a2 |= m2 & k2;
            a3 |= m3 & k3;
        }
        // lower-triangle words are garbage (k_mask writes cb>=rb only): gate
        if (lane >= w) remv |= (a0 | a1) | (a2 | a3);

        __builtin_amdgcn_sched_barrier(0);
        cur ^= 1;
    }

    // epilogue: scatter kept scores back to original index order
    sh[lane] = remv;
    __syncthreads();
    const unsigned short* ord = order + c * NN;
    for (int t = 0; t < 64; ++t) {
        int p = t * 64 + lane;
        bool kp = !((sh[t] >> lane) & 1);
        float s = ss[p];
        int oi = ord[p];
        kept[c * NN + oi] = kp ? s : 0.f;
    }
}

// K5: exact 100th-largest of 20480 via 32-step bitwise radix select + final write.
__global__ void __launch_bounds__(1024) k_topk_final(const float* __restrict__ kept,
                                                     float* __restrict__ out) {
    int tid = threadIdx.x;
    uint32_t v[20];
#pragma unroll
    for (int k = 0; k < 20; ++k) v[k] = fmap(kept[k * 1024 + tid]);
    __shared__ int red[16];
    __shared__ int tot;
    uint32_t pre = 0;
    for (int bit = 31; bit >= 0; --bit) {
        uint32_t cand = pre | (1u << bit);
        int cnt = 0;
#pragma unroll
        for (int k = 0; k < 20; ++k) cnt += (v[k] >= cand);
#pragma unroll
        for (int off = 32; off; off >>= 1) cnt += __shfl_down(cnt, off, 64);
        if ((tid & 63) == 0) red[tid >> 6] = cnt;
        __syncthreads();
        if (tid == 0) {
            int s = 0;
            for (int q = 0; q < 16; ++q) s += red[q];
            tot = s;
        }
        __syncthreads();
        if (tot >= 100) pre = cand;
    }
    // final column write: keep iff mapped value >= pre (exact reference semantics)
#pragma unroll
    for (int k = 0; k < 20; ++k) {
        int idx = k * 1024 + tid;
        int c = idx >> 12;
        int i = idx & (NN - 1);
        out[((size_t)c * NN + i) * 7 + 6] = (v[k] >= pre) ? funmap(v[k]) : 0.f;
    }
}

extern "C" void kernel_launch(void* const* d_in, const int* in_sizes, int n_in,
                              void* d_out, int out_size, void* d_ws, size_t ws_size,
                              hipStream_t stream) {
    const float* prop = (const float*)d_in[0];   // (4096,7)
    const float* pred = (const float*)d_in[1];   // (4096,36)
    const float* cls = (const float*)d_in[2];    // (4096,6)
    float* out = (float*)d_out;                  // (5,4096,7)

    // workspace layout (total 11MB)
    char* base = (char*)d_ws;
    uint64_t* skey = (uint64_t*)base;                         // 160KB [0,160K)
    uint64_t* diag = (uint64_t*)(base + (160ull << 10));      // 160KB [160K,320K)
    float* sscores = (float*)(base + (320ull << 10));         // 80KB  [320K,400K)
    float* kept = (float*)(base + (400ull << 10));            // 80KB  [400K,480K)
    unsigned short* order = (unsigned short*)(base + (480ull << 10)); // 40KB [480K,520K)
    float* sboxes = (float*)(base + (528ull << 10));          // 480KB [528K,1008K)
    uint64_t* mask = (uint64_t*)(base + (1ull << 20));        // 10MB  [1M,11M)

    k_prep<<<dim3(16), dim3(256), 0, stream>>>(prop, pred, cls, out, skey);
    k_sort<<<dim3(16, NCLS), dim3(256), 0, stream>>>(skey, out, sscores, order, sboxes);
    k_mask<<<dim3(16, 64, NCLS), dim3(256), 0, stream>>>(sboxes, mask, diag);
    k_nms<<<dim3(NCLS), dim3(64), 0, stream>>>(sscores, order, mask, diag, kept);
    k_topk_final<<<dim3(1), dim3(1024), 0, stream>>>(kept, out);
}

// Round 11
// 411.613 us; speedup vs baseline: 1.3141x; 1.3141x over previous
//
#include <hip/hip_runtime.h>
#include <stdint.h>

#define NN 4096
#define NCLS 5
#define NWORD 64
#define SCORE_TH 0.05f
#define NMS_TH 0.3f

// monotone f32 -> u32 map (order-preserving, handles sign)
__device__ __forceinline__ uint32_t fmap(float f) {
    uint32_t u = __float_as_uint(f);
    return (u & 0x80000000u) ? ~u : (u | 0x80000000u);
}
__device__ __forceinline__ float funmap(uint32_t m) {
    uint32_t u = (m & 0x80000000u) ? (m & 0x7fffffffu) : ~m;
    return __uint_as_float(u);
}

// K1: softmax + bbox transform + clip. Writes out cols 0..5 and u64 sort keys.
__global__ void k_prep(const float* __restrict__ prop, const float* __restrict__ pred,
                       const float* __restrict__ cls, float* __restrict__ out,
                       uint64_t* __restrict__ skey) {
    int i = blockIdx.x * 256 + threadIdx.x;
    if (i >= NN) return;
    const float* pr = prop + i * 7;
    float l0 = pr[1], l1 = pr[2], l2 = pr[3];
    float h0 = pr[4], h1 = pr[5], h2 = pr[6];
    float s0 = h0 - l0 + 1.f, s1 = h1 - l1 + 1.f, s2 = h2 - l2 + 1.f;
    float c0 = l0 + 0.5f * s0, c1 = l1 + 0.5f * s1, c2 = l2 + 0.5f * s2;

    float sc[6];
    float mx = -3.4e38f;
#pragma unroll
    for (int c = 0; c < 6; ++c) { sc[c] = cls[i * 6 + c]; mx = fmaxf(mx, sc[c]); }
    float sum = 0.f;
#pragma unroll
    for (int c = 0; c < 6; ++c) { sc[c] = expf(sc[c] - mx); sum += sc[c]; }
    float inv = 1.f / sum;

#pragma unroll
    for (int c = 1; c < 6; ++c) {
        const float* d = pred + i * 36 + c * 6;
        float dc0 = d[0] / 10.f, dc1 = d[1] / 10.f, dc2 = d[2] / 10.f;
        float ds0 = d[3] / 5.f, ds1 = d[4] / 5.f, ds2 = d[5] / 5.f;
        float pc0 = dc0 * s0 + c0, pc1 = dc1 * s1 + c1, pc2 = dc2 * s2 + c2;
        float ps0 = expf(ds0) * s0, ps1 = expf(ds1) * s1, ps2 = expf(ds2) * s2;
        float o0 = fminf(fmaxf(pc0 - 0.5f * ps0, 0.f), 1023.f);
        float o1 = fminf(fmaxf(pc1 - 0.5f * ps1, 0.f), 1023.f);
        float o2 = fminf(fmaxf(pc2 - 0.5f * ps2, 0.f), 1023.f);
        float o3 = fminf(fmaxf(pc0 + 0.5f * ps0 - 1.f, 0.f), 1023.f);
        float o4 = fminf(fmaxf(pc1 + 0.5f * ps1 - 1.f, 0.f), 1023.f);
        float o5 = fminf(fmaxf(pc2 + 0.5f * ps2 - 1.f, 0.f), 1023.f);
        float* ob = out + ((size_t)(c - 1) * NN + i) * 7;
        ob[0] = o0; ob[1] = o1; ob[2] = o2; ob[3] = o3; ob[4] = o4; ob[5] = o5;
        float score = sc[c] * inv;
        // key: (mapped score desc, index asc) -> single u64 greater-than compare
        skey[(c - 1) * NN + i] = ((uint64_t)fmap(score) << 12) | (uint32_t)(4095 - i);
    }
}

// K2: O(N^2) counting rank-sort via u64 keys.
__global__ void __launch_bounds__(256) k_sort(const uint64_t* __restrict__ skey,
                                              const float* __restrict__ out,
                                              float* __restrict__ sscores,
                                              unsigned short* __restrict__ order,
                                              float* __restrict__ sboxes) {
    int c = blockIdx.y;
    int i = blockIdx.x * 256 + threadIdx.x;
    const uint64_t* K = skey + c * NN;
    uint64_t ki = K[i];
    int rank = 0;
#pragma unroll 2
    for (int j = 0; j < NN; j += 8) {
        uint64_t k0 = K[j], k1 = K[j + 1], k2 = K[j + 2], k3 = K[j + 3];
        uint64_t k4 = K[j + 4], k5 = K[j + 5], k6 = K[j + 6], k7 = K[j + 7];
        int a = (k0 > ki) + (k1 > ki) + (k2 > ki) + (k3 > ki);
        int b = (k4 > ki) + (k5 > ki) + (k6 > ki) + (k7 > ki);
        rank += a + b;
    }
    int io = c * NN + rank;
    order[io] = (unsigned short)i;
    sscores[io] = funmap((uint32_t)(ki >> 12));
    const float* b = out + ((size_t)c * NN + i) * 7;
    float* sb = sboxes + (size_t)io * 6;
#pragma unroll
    for (int k = 0; k < 6; ++k) sb[k] = b[k];
}

// K3: suppression bitmask, UPPER TRIANGLE ONLY (cb>=rb). 4 waves/block.
__global__ void __launch_bounds__(256) k_mask(const float* __restrict__ sboxes,
                                              uint64_t* __restrict__ mask,
                                              uint64_t* __restrict__ diag) {
    int tid = threadIdx.x;
    int wid = tid >> 6, lane = tid & 63;
    int rb = blockIdx.y, c = blockIdx.z;
    int cb = rb + blockIdx.x * 4 + wid;
    bool active = (cb < 64);

    __shared__ float cB[4][64][6];
    __shared__ float cV[4][64];

    int r = rb * 64 + lane;
    float rl0 = 0, rl1 = 0, rl2 = 0, rh0 = 0, rh1 = 0, rh2 = 0, vi = 0;
    if (active) {
        const float* rp = sboxes + ((size_t)c * NN + r) * 6;
        rl0 = rp[0]; rl1 = rp[1]; rl2 = rp[2];
        rh0 = rp[3]; rh1 = rp[4]; rh2 = rp[5];
        vi = (rh0 - rl0 + 1.f) * (rh1 - rl1 + 1.f) * (rh2 - rl2 + 1.f);
        const float* cp = sboxes + ((size_t)c * NN + cb * 64 + lane) * 6;
#pragma unroll
        for (int k = 0; k < 6; ++k) cB[wid][lane][k] = cp[k];
        cV[wid][lane] = (cB[wid][lane][3] - cB[wid][lane][0] + 1.f) *
                        (cB[wid][lane][4] - cB[wid][lane][1] + 1.f) *
                        (cB[wid][lane][5] - cB[wid][lane][2] + 1.f);
    }
    __syncthreads();
    if (!active) return;

    uint64_t bits = 0;
    for (int j2 = 0; j2 < 64; ++j2) {
        int j = cb * 64 + j2;
        if (j > r) {
            float w0 = fmaxf(fminf(rh0, cB[wid][j2][3]) - fmaxf(rl0, cB[wid][j2][0]) + 1.f, 0.f);
            float w1 = fmaxf(fminf(rh1, cB[wid][j2][4]) - fmaxf(rl1, cB[wid][j2][1]) + 1.f, 0.f);
            float w2 = fmaxf(fminf(rh2, cB[wid][j2][5]) - fmaxf(rl2, cB[wid][j2][2]) + 1.f, 0.f);
            float inter = w0 * w1 * w2;
            float iou = inter / (vi + cV[wid][j2] - inter);
            if (iou > NMS_TH) bits |= 1ull << j2;
        }
    }
    mask[((size_t)c * NN + r) * NWORD + cb] = bits;
    if (cb == rb) diag[(size_t)c * NN + r] = bits;
}

// K4: sequential greedy reduce, one wave per class.
// R3/R4/R10 lesson: >=128 staging VGPRs live -> allocator spills (scratch,
// ~131cy/load). R5/R6 lesson: global_load_lds queue is depth-~2 for one wave.
// This version: NO mask tile staging at all. Per round, two 16xu64 register
// groups (64 VGPRs max live) of direct-global b64 gathers (L2-resident mask),
// issued ahead and consumed after the register-only readlane chain sub-block
// that computes their gate bits. Anti-dependency (reissue into consumed
// buffer) caps live registers; counted vmcnt waits come from the compiler.
__global__ void __launch_bounds__(64, 1) k_nms(const float* __restrict__ sscores,
                                               const unsigned short* __restrict__ order,
                                               const uint64_t* __restrict__ mask,
                                               const uint64_t* __restrict__ diag,
                                               float* __restrict__ kept) {
    __shared__ __align__(16) uint64_t ldiag[NN];  // 32KB
    __shared__ uint64_t sh[64];

    int c = blockIdx.x;
    int lane = threadIdx.x;
    const uint64_t* M = mask + (size_t)c * NN * NWORD;
    const uint64_t* D = diag + (size_t)c * NN;
    const float* ss = sscores + c * NN;

    // prologue: stage ldiag (32KB) via 8-deep reg chunks (32 VGPRs live)
    {
        const uint4* g = (const uint4*)D;
        uint4* l = (uint4*)ldiag;
#pragma unroll 1
        for (int i = 0; i < 32; i += 8) {
            uint4 t0 = g[(i + 0) * 64 + lane], t1 = g[(i + 1) * 64 + lane];
            uint4 t2 = g[(i + 2) * 64 + lane], t3 = g[(i + 3) * 64 + lane];
            uint4 t4 = g[(i + 4) * 64 + lane], t5 = g[(i + 5) * 64 + lane];
            uint4 t6 = g[(i + 6) * 64 + lane], t7 = g[(i + 7) * 64 + lane];
            l[(i + 0) * 64 + lane] = t0; l[(i + 1) * 64 + lane] = t1;
            l[(i + 2) * 64 + lane] = t2; l[(i + 3) * 64 + lane] = t3;
            l[(i + 4) * 64 + lane] = t4; l[(i + 5) * 64 + lane] = t5;
            l[(i + 6) * 64 + lane] = t6; l[(i + 7) * 64 + lane] = t7;
        }
    }

    // init remv: lane l owns word l = indices l*64..l*64+63; bit j = !(score>TH)
    uint64_t remv = 0;
    {
        const float4* sl = (const float4*)(ss + lane * 64);
#pragma unroll
        for (int q = 0; q < 16; ++q) {
            float4 v = sl[q];
            if (!(v.x > SCORE_TH)) remv |= 1ull << (q * 4);
            if (!(v.y > SCORE_TH)) remv |= 1ull << (q * 4 + 1);
            if (!(v.z > SCORE_TH)) remv |= 1ull << (q * 4 + 2);
            if (!(v.w > SCORE_TH)) remv |= 1ull << (q * 4 + 3);
        }
    }
    __builtin_amdgcn_s_barrier();  // ldiag visible (single wave; cheap anyway)

#define ISSUE16(buf, base)                                          \
    _Pragma("unroll") for (int i_ = 0; i_ < 16; ++i_) {             \
        buf[i_] = R[(((base) + i_) << 6) | lane];                   \
    }

#define CHAIN16(base)                                               \
    {                                                               \
        uint32_t lo_[16], hi_[16];                                  \
        _Pragma("unroll") for (int b_ = 0; b_ < 16; ++b_) {         \
            lo_[b_] = __builtin_amdgcn_readlane(dgl, (base) + b_);  \
            hi_[b_] = __builtin_amdgcn_readlane(dgh, (base) + b_);  \
        }                                                           \
        _Pragma("unroll") for (int b_ = 0; b_ < 16; ++b_) {         \
            int bb_ = (base) + b_;                                  \
            if (!((rw >> bb_) & 1)) {                               \
                rw |= ((uint64_t)hi_[b_] << 32) | lo_[b_];          \
                kmask |= 1ull << bb_;                               \
            }                                                       \
        }                                                           \
    }

#define CONSUME16(buf, base, acc)                                   \
    _Pragma("unroll") for (int i_ = 0; i_ < 16; ++i_) {             \
        uint64_t kb_ = 0ull - ((kmask >> ((base) + i_)) & 1ull);    \
        acc |= buf[i_] & kb_;                                       \
    }

#pragma unroll 1
    for (int w = 0; w < 64; ++w) {
        const uint64_t* R = M + ((size_t)w << 12);  // rows w*64.., col word lane
        uint64_t gA[16], gB[16];

        // issue rows 0-31 (32 b64 loads in flight, 64 VGPRs)
        ISSUE16(gA, 0)
        ISSUE16(gB, 16)
        __builtin_amdgcn_sched_barrier(0);

        // register-only serial keep-chain, interleaved with gather groups
        uint32_t rlo = __builtin_amdgcn_readlane((uint32_t)remv, w);
        uint32_t rhi = __builtin_amdgcn_readlane((uint32_t)(remv >> 32), w);
        uint64_t rw = ((uint64_t)rhi << 32) | rlo;
        uint64_t mydg = ldiag[(w << 6) | lane];  // one lane-distributed ds_read
        uint32_t dgl = (uint32_t)mydg, dgh = (uint32_t)(mydg >> 32);
        uint64_t kmask = 0;
        uint64_t a0 = 0, a1 = 0, a2 = 0, a3 = 0;

        CHAIN16(0)                 // covers gA's L2 latency
        CONSUME16(gA, 0, a0)
        ISSUE16(gA, 32)            // reuse gA regs (anti-dep caps pressure)
        CHAIN16(16)
        CONSUME16(gB, 16, a1)
        ISSUE16(gB, 48)
        CHAIN16(32)
        CONSUME16(gA, 32, a2)
        CHAIN16(48)
        CONSUME16(gB, 48, a3)

        // lower-triangle words are garbage (k_mask writes cb>=rb only): gate
        if (lane >= w) remv |= (a0 | a1) | (a2 | a3);
    }

#undef ISSUE16
#undef CHAIN16
#undef CONSUME16

    // epilogue: scatter kept scores back to original index order
    sh[lane] = remv;
    __syncthreads();
    const unsigned short* ord = order + c * NN;
    for (int t = 0; t < 64; ++t) {
        int p = t * 64 + lane;
        bool kp = !((sh[t] >> lane) & 1);
        float s = ss[p];
        int oi = ord[p];
        kept[c * NN + oi] = kp ? s : 0.f;
    }
}

// K5: exact 100th-largest of 20480 via 32-step bitwise radix select + final write.
__global__ void __launch_bounds__(1024) k_topk_final(const float* __restrict__ kept,
                                                     float* __restrict__ out) {
    int tid = threadIdx.x;
    uint32_t v[20];
#pragma unroll
    for (int k = 0; k < 20; ++k) v[k] = fmap(kept[k * 1024 + tid]);
    __shared__ int red[16];
    __shared__ int tot;
    uint32_t pre = 0;
    for (int bit = 31; bit >= 0; --bit) {
        uint32_t cand = pre | (1u << bit);
        int cnt = 0;
#pragma unroll
        for (int k = 0; k < 20; ++k) cnt += (v[k] >= cand);
#pragma unroll
        for (int off = 32; off; off >>= 1) cnt += __shfl_down(cnt, off, 64);
        if ((tid & 63) == 0) red[tid >> 6] = cnt;
        __syncthreads();
        if (tid == 0) {
            int s = 0;
            for (int q = 0; q < 16; ++q) s += red[q];
            tot = s;
        }
        __syncthreads();
        if (tot >= 100) pre = cand;
    }
    // final column write: keep iff mapped value >= pre (exact reference semantics)
#pragma unroll
    for (int k = 0; k < 20; ++k) {
        int idx = k * 1024 + tid;
        int c = idx >> 12;
        int i = idx & (NN - 1);
        out[((size_t)c * NN + i) * 7 + 6] = (v[k] >= pre) ? funmap(v[k]) : 0.f;
    }
}

extern "C" void kernel_launch(void* const* d_in, const int* in_sizes, int n_in,
                              void* d_out, int out_size, void* d_ws, size_t ws_size,
                              hipStream_t stream) {
    const float* prop = (const float*)d_in[0];   // (4096,7)
    const float* pred = (const float*)d_in[1];   // (4096,36)
    const float* cls = (const float*)d_in[2];    // (4096,6)
    float* out = (float*)d_out;                  // (5,4096,7)

    // workspace layout (total 11MB)
    char* base = (char*)d_ws;
    uint64_t* skey = (uint64_t*)base;                         // 160KB [0,160K)
    uint64_t* diag = (uint64_t*)(base + (160ull << 10));      // 160KB [160K,320K)
    float* sscores = (float*)(base + (320ull << 10));         // 80KB  [320K,400K)
    float* kept = (float*)(base + (400ull << 10));            // 80KB  [400K,480K)
    unsigned short* order = (unsigned short*)(base + (480ull << 10)); // 40KB [480K,520K)
    float* sboxes = (float*)(base + (528ull << 10));          // 480KB [528K,1008K)
    uint64_t* mask = (uint64_t*)(base + (1ull << 20));        // 10MB  [1M,11M)

    k_prep<<<dim3(16), dim3(256), 0, stream>>>(prop, pred, cls, out, skey);
    k_sort<<<dim3(16, NCLS), dim3(256), 0, stream>>>(skey, out, sscores, order, sboxes);
    k_mask<<<dim3(16, 64, NCLS), dim3(256), 0, stream>>>(sboxes, mask, diag);
    k_nms<<<dim3(NCLS), dim3(64), 0, stream>>>(sscores, order, mask, diag, kept);
    k_topk_final<<<dim3(1), dim3(1024), 0, stream>>>(kept, out);
}

// Round 13
// 393.322 us; speedup vs baseline: 1.3752x; 1.0465x over previous
//
#include <hip/hip_runtime.h>
#include <stdint.h>

#define NN 4096
#define NCLS 5
#define NWORD 64
#define SCORE_TH 0.05f
#define NMS_TH 0.3f

// monotone f32 -> u32 map (order-preserving, handles sign)
__device__ __forceinline__ uint32_t fmap(float f) {
    uint32_t u = __float_as_uint(f);
    return (u & 0x80000000u) ? ~u : (u | 0x80000000u);
}
__device__ __forceinline__ float funmap(uint32_t m) {
    uint32_t u = (m & 0x80000000u) ? (m & 0x7fffffffu) : ~m;
    return __uint_as_float(u);
}

// K1: softmax + bbox transform + clip. Writes out cols 0..5 and u64 sort keys.
__global__ void k_prep(const float* __restrict__ prop, const float* __restrict__ pred,
                       const float* __restrict__ cls, float* __restrict__ out,
                       uint64_t* __restrict__ skey) {
    int i = blockIdx.x * 256 + threadIdx.x;
    if (i >= NN) return;
    const float* pr = prop + i * 7;
    float l0 = pr[1], l1 = pr[2], l2 = pr[3];
    float h0 = pr[4], h1 = pr[5], h2 = pr[6];
    float s0 = h0 - l0 + 1.f, s1 = h1 - l1 + 1.f, s2 = h2 - l2 + 1.f;
    float c0 = l0 + 0.5f * s0, c1 = l1 + 0.5f * s1, c2 = l2 + 0.5f * s2;

    float sc[6];
    float mx = -3.4e38f;
#pragma unroll
    for (int c = 0; c < 6; ++c) { sc[c] = cls[i * 6 + c]; mx = fmaxf(mx, sc[c]); }
    float sum = 0.f;
#pragma unroll
    for (int c = 0; c < 6; ++c) { sc[c] = expf(sc[c] - mx); sum += sc[c]; }
    float inv = 1.f / sum;

#pragma unroll
    for (int c = 1; c < 6; ++c) {
        const float* d = pred + i * 36 + c * 6;
        float dc0 = d[0] / 10.f, dc1 = d[1] / 10.f, dc2 = d[2] / 10.f;
        float ds0 = d[3] / 5.f, ds1 = d[4] / 5.f, ds2 = d[5] / 5.f;
        float pc0 = dc0 * s0 + c0, pc1 = dc1 * s1 + c1, pc2 = dc2 * s2 + c2;
        float ps0 = expf(ds0) * s0, ps1 = expf(ds1) * s1, ps2 = expf(ds2) * s2;
        float o0 = fminf(fmaxf(pc0 - 0.5f * ps0, 0.f), 1023.f);
        float o1 = fminf(fmaxf(pc1 - 0.5f * ps1, 0.f), 1023.f);
        float o2 = fminf(fmaxf(pc2 - 0.5f * ps2, 0.f), 1023.f);
        float o3 = fminf(fmaxf(pc0 + 0.5f * ps0 - 1.f, 0.f), 1023.f);
        float o4 = fminf(fmaxf(pc1 + 0.5f * ps1 - 1.f, 0.f), 1023.f);
        float o5 = fminf(fmaxf(pc2 + 0.5f * ps2 - 1.f, 0.f), 1023.f);
        float* ob = out + ((size_t)(c - 1) * NN + i) * 7;
        ob[0] = o0; ob[1] = o1; ob[2] = o2; ob[3] = o3; ob[4] = o4; ob[5] = o5;
        float score = sc[c] * inv;
        // key: (mapped score desc, index asc) -> single u64 greater-than compare
        skey[(c - 1) * NN + i] = ((uint64_t)fmap(score) << 12) | (uint32_t)(4095 - i);
    }
}

// K2: O(N^2) counting rank-sort via u64 keys.
__global__ void __launch_bounds__(256) k_sort(const uint64_t* __restrict__ skey,
                                              const float* __restrict__ out,
                                              float* __restrict__ sscores,
                                              unsigned short* __restrict__ order,
                                              float* __restrict__ sboxes) {
    int c = blockIdx.y;
    int i = blockIdx.x * 256 + threadIdx.x;
    const uint64_t* K = skey + c * NN;
    uint64_t ki = K[i];
    int rank = 0;
#pragma unroll 2
    for (int j = 0; j < NN; j += 8) {
        uint64_t k0 = K[j], k1 = K[j + 1], k2 = K[j + 2], k3 = K[j + 3];
        uint64_t k4 = K[j + 4], k5 = K[j + 5], k6 = K[j + 6], k7 = K[j + 7];
        int a = (k0 > ki) + (k1 > ki) + (k2 > ki) + (k3 > ki);
        int b = (k4 > ki) + (k5 > ki) + (k6 > ki) + (k7 > ki);
        rank += a + b;
    }
    int io = c * NN + rank;
    order[io] = (unsigned short)i;
    sscores[io] = funmap((uint32_t)(ki >> 12));
    const float* b = out + ((size_t)c * NN + i) * 7;
    float* sb = sboxes + (size_t)io * 6;
#pragma unroll
    for (int k = 0; k < 6; ++k) sb[k] = b[k];
}

// K3: suppression bitmask, UPPER TRIANGLE ONLY (cb>=rb). 4 waves/block.
__global__ void __launch_bounds__(256) k_mask(const float* __restrict__ sboxes,
                                              uint64_t* __restrict__ mask,
                                              uint64_t* __restrict__ diag) {
    int tid = threadIdx.x;
    int wid = tid >> 6, lane = tid & 63;
    int rb = blockIdx.y, c = blockIdx.z;
    int cb = rb + blockIdx.x * 4 + wid;
    bool active = (cb < 64);

    __shared__ float cB[4][64][6];
    __shared__ float cV[4][64];

    int r = rb * 64 + lane;
    float rl0 = 0, rl1 = 0, rl2 = 0, rh0 = 0, rh1 = 0, rh2 = 0, vi = 0;
    if (active) {
        const float* rp = sboxes + ((size_t)c * NN + r) * 6;
        rl0 = rp[0]; rl1 = rp[1]; rl2 = rp[2];
        rh0 = rp[3]; rh1 = rp[4]; rh2 = rp[5];
        vi = (rh0 - rl0 + 1.f) * (rh1 - rl1 + 1.f) * (rh2 - rl2 + 1.f);
        const float* cp = sboxes + ((size_t)c * NN + cb * 64 + lane) * 6;
#pragma unroll
        for (int k = 0; k < 6; ++k) cB[wid][lane][k] = cp[k];
        cV[wid][lane] = (cB[wid][lane][3] - cB[wid][lane][0] + 1.f) *
                        (cB[wid][lane][4] - cB[wid][lane][1] + 1.f) *
                        (cB[wid][lane][5] - cB[wid][lane][2] + 1.f);
    }
    __syncthreads();
    if (!active) return;

    uint64_t bits = 0;
    for (int j2 = 0; j2 < 64; ++j2) {
        int j = cb * 64 + j2;
        if (j > r) {
            float w0 = fmaxf(fminf(rh0, cB[wid][j2][3]) - fmaxf(rl0, cB[wid][j2][0]) + 1.f, 0.f);
            float w1 = fmaxf(fminf(rh1, cB[wid][j2][4]) - fmaxf(rl1, cB[wid][j2][1]) + 1.f, 0.f);
            float w2 = fmaxf(fminf(rh2, cB[wid][j2][5]) - fmaxf(rl2, cB[wid][j2][2]) + 1.f, 0.f);
            float inter = w0 * w1 * w2;
            float iou = inter / (vi + cV[wid][j2] - inter);
            if (iou > NMS_TH) bits |= 1ull << j2;
        }
    }
    mask[((size_t)c * NN + r) * NWORD + cb] = bits;
    if (cb == rb) diag[(size_t)c * NN + r] = bits;
}

// raw barrier: does NOT drain vmcnt (in-flight global loads survive), only LDS.
#define NMS_BARRIER()                                        \
    do {                                                     \
        asm volatile("s_waitcnt lgkmcnt(0)" ::: "memory");   \
        __builtin_amdgcn_s_barrier();                        \
        asm volatile("" ::: "memory");                       \
    } while (0)

// K4: 4-wave cooperative greedy reduce, one block (256 thr) per class.
// R11 lesson: one wave caps at ~32 rows in flight (64 VGPRs) -> ~4 exposed L2
// latencies/round (5.7Kcy). Here wave v owns rows v*16..v*16+15 (32 staging
// VGPRs each, 64 rows in flight block-wide) prefetched a FULL round (~1Kcy >
// L2 ~500cy) ahead. Wave0 runs the register-only readlane chain; kmask
// broadcast via LDS; per-wave racc partials merged lazily (word w+1 only).
// Raw s_barrier + lgkmcnt keeps global loads un-drained across barriers.
__global__ void __launch_bounds__(256, 1) k_nms(const float* __restrict__ sscores,
                                                const unsigned short* __restrict__ order,
                                                const uint64_t* __restrict__ mask,
                                                const uint64_t* __restrict__ diag,
                                                float* __restrict__ kept) {
    __shared__ __align__(16) uint64_t ldiag[NN];  // 32KB
    __shared__ uint64_t slot[4];
    __shared__ uint64_t pacc[4][64];
    __shared__ uint64_t sh[64];
    __shared__ uint32_t km_sh[2];

    int tid = threadIdx.x;
    int wid = tid >> 6, lane = tid & 63;
    int c = blockIdx.x;
    const uint64_t* M = mask + (size_t)c * NN * NWORD;
    const uint64_t* D = diag + (size_t)c * NN;
    const float* ss = sscores + c * NN;

    // cooperative ldiag staging: wave wid stages uint4-rows wid*8..wid*8+7
    {
        const uint4* g = (const uint4*)D;
        uint4* l = (uint4*)ldiag;
        uint4 t0 = g[(wid * 8 + 0) * 64 + lane], t1 = g[(wid * 8 + 1) * 64 + lane];
        uint4 t2 = g[(wid * 8 + 2) * 64 + lane], t3 = g[(wid * 8 + 3) * 64 + lane];
        uint4 t4 = g[(wid * 8 + 4) * 64 + lane], t5 = g[(wid * 8 + 5) * 64 + lane];
        uint4 t6 = g[(wid * 8 + 6) * 64 + lane], t7 = g[(wid * 8 + 7) * 64 + lane];
        l[(wid * 8 + 0) * 64 + lane] = t0; l[(wid * 8 + 1) * 64 + lane] = t1;
        l[(wid * 8 + 2) * 64 + lane] = t2; l[(wid * 8 + 3) * 64 + lane] = t3;
        l[(wid * 8 + 4) * 64 + lane] = t4; l[(wid * 8 + 5) * 64 + lane] = t5;
        l[(wid * 8 + 6) * 64 + lane] = t6; l[(wid * 8 + 7) * 64 + lane] = t7;
    }

    // wave0: score-init word (lane l owns word l; bit j = !(score>TH))
    uint64_t initW = 0;
    if (wid == 0) {
        const float4* sl = (const float4*)(ss + lane * 64);
#pragma unroll
        for (int q = 0; q < 16; ++q) {
            float4 v = sl[q];
            if (!(v.x > SCORE_TH)) initW |= 1ull << (q * 4);
            if (!(v.y > SCORE_TH)) initW |= 1ull << (q * 4 + 1);
            if (!(v.z > SCORE_TH)) initW |= 1ull << (q * 4 + 2);
            if (!(v.w > SCORE_TH)) initW |= 1ull << (q * 4 + 3);
        }
    }
    if (tid < 4) slot[tid] = 0;

    // prefetch round-0 rows: wave wid owns rows wid*16..wid*16+15, col word lane
    uint64_t g0[16];
#pragma unroll
    for (int i = 0; i < 16; ++i) g0[i] = M[((wid * 16 + i) << 6) | lane];

    NMS_BARRIER();  // ldiag + slot visible (global loads stay in flight)

#define CHAIN16(base)                                               \
    {                                                               \
        uint32_t lo_[16], hi_[16];                                  \
        _Pragma("unroll") for (int b_ = 0; b_ < 16; ++b_) {         \
            lo_[b_] = __builtin_amdgcn_readlane(dgl, (base) + b_);  \
            hi_[b_] = __builtin_amdgcn_readlane(dgh, (base) + b_);  \
        }                                                           \
        _Pragma("unroll") for (int b_ = 0; b_ < 16; ++b_) {         \
            int bb_ = (base) + b_;                                  \
            if (!((rw >> bb_) & 1)) {                               \
                rw |= ((uint64_t)hi_[b_] << 32) | lo_[b_];          \
                kmask |= 1ull << bb_;                               \
            }                                                       \
        }                                                           \
    }

    uint64_t racc = 0;
#pragma unroll 1
    for (int w = 0; w < 64; ++w) {
        // --- phase A (wave0): register-only serial keep-chain ---
        if (wid == 0) {
            uint32_t ilo = __builtin_amdgcn_readlane((uint32_t)initW, w);
            uint32_t ihi = __builtin_amdgcn_readlane((uint32_t)(initW >> 32), w);
            uint64_t rw = (((uint64_t)ihi << 32) | ilo) |
                          slot[0] | slot[1] | slot[2] | slot[3];
            uint64_t mydg = ldiag[(w << 6) | lane];  // one lane-distributed ds_read
            uint32_t dgl = (uint32_t)mydg, dgh = (uint32_t)(mydg >> 32);
            uint64_t kmask = 0;
            CHAIN16(0) CHAIN16(16) CHAIN16(32) CHAIN16(48)
            if (lane == 0) {
                km_sh[0] = (uint32_t)kmask;
                km_sh[1] = (uint32_t)(kmask >> 32);
            }
        }
        NMS_BARRIER();

        // --- phase B (all waves): consume prefetched rows, prefetch, publish ---
        uint64_t kmask = ((uint64_t)km_sh[1] << 32) | km_sh[0];
        uint64_t a = 0;
#pragma unroll
        for (int i = 0; i < 16; ++i) {
            uint64_t kb = 0ull - ((kmask >> (wid * 16 + i)) & 1ull);
            a |= g0[i] & kb;
        }
        if (lane >= w) racc |= a;  // lower-triangle words are garbage: gate

        if (w < 63) {
            const uint64_t* R = M + ((size_t)(w + 1) << 12);
#pragma unroll
            for (int i = 0; i < 16; ++i) g0[i] = R[((wid * 16 + i) << 6) | lane];
            // publish this wave's remv word w+1 for next round's chain
            uint32_t plo = __builtin_amdgcn_readlane((uint32_t)racc, w + 1);
            uint32_t phi = __builtin_amdgcn_readlane((uint32_t)(racc >> 32), w + 1);
            if (lane == 0) slot[wid] = ((uint64_t)phi << 32) | plo;
        }
        NMS_BARRIER();
    }
#undef CHAIN16

    // merge partials and scatter kept scores back to original index order
    pacc[wid][lane] = racc;
    NMS_BARRIER();
    if (wid == 0)
        sh[lane] = initW | pacc[0][lane] | pacc[1][lane] | pacc[2][lane] | pacc[3][lane];
    NMS_BARRIER();
    const unsigned short* ord = order + c * NN;
#pragma unroll
    for (int tt = 0; tt < 16; ++tt) {
        int t = wid * 16 + tt;
        int p = t * 64 + lane;
        bool kp = !((sh[t] >> lane) & 1);
        float s = ss[p];
        int oi = ord[p];
        kept[c * NN + oi] = kp ? s : 0.f;
    }
}

// K5: exact 100th-largest of 20480 via 32-step bitwise radix select + final write.
__global__ void __launch_bounds__(1024) k_topk_final(const float* __restrict__ kept,
                                                     float* __restrict__ out) {
    int tid = threadIdx.x;
    uint32_t v[20];
#pragma unroll
    for (int k = 0; k < 20; ++k) v[k] = fmap(kept[k * 1024 + tid]);
    __shared__ int red[16];
    __shared__ int tot;
    uint32_t pre = 0;
    for (int bit = 31; bit >= 0; --bit) {
        uint32_t cand = pre | (1u << bit);
        int cnt = 0;
#pragma unroll
        for (int k = 0; k < 20; ++k) cnt += (v[k] >= cand);
#pragma unroll
        for (int off = 32; off; off >>= 1) cnt += __shfl_down(cnt, off, 64);
        if ((tid & 63) == 0) red[tid >> 6] = cnt;
        __syncthreads();
        if (tid == 0) {
            int s = 0;
            for (int q = 0; q < 16; ++q) s += red[q];
            tot = s;
        }
        __syncthreads();
        if (tot >= 100) pre = cand;
    }
    // final column write: keep iff mapped value >= pre (exact reference semantics)
#pragma unroll
    for (int k = 0; k < 20; ++k) {
        int idx = k * 1024 + tid;
        int c = idx >> 12;
        int i = idx & (NN - 1);
        out[((size_t)c * NN + i) * 7 + 6] = (v[k] >= pre) ? funmap(v[k]) : 0.f;
    }
}

extern "C" void kernel_launch(void* const* d_in, const int* in_sizes, int n_in,
                              void* d_out, int out_size, void* d_ws, size_t ws_size,
                              hipStream_t stream) {
    const float* prop = (const float*)d_in[0];   // (4096,7)
    const float* pred = (const float*)d_in[1];   // (4096,36)
    const float* cls = (const float*)d_in[2];    // (4096,6)
    float* out = (float*)d_out;                  // (5,4096,7)

    // workspace layout (total 11MB)
    char* base = (char*)d_ws;
    uint64_t* skey = (uint64_t*)base;                         // 160KB [0,160K)
    uint64_t* diag = (uint64_t*)(base + (160ull << 10));      // 160KB [160K,320K)
    float* sscores = (float*)(base + (320ull << 10));         // 80KB  [320K,400K)
    float* kept = (float*)(base + (400ull << 10));            // 80KB  [400K,480K)
    unsigned short* order = (unsigned short*)(base + (480ull << 10)); // 40KB [480K,520K)
    float* sboxes = (float*)(base + (528ull << 10));          // 480KB [528K,1008K)
    uint64_t* mask = (uint64_t*)(base + (1ull << 20));        // 10MB  [1M,11M)

    k_prep<<<dim3(16), dim3(256), 0, stream>>>(prop, pred, cls, out, skey);
    k_sort<<<dim3(16, NCLS), dim3(256), 0, stream>>>(skey, out, sscores, order, sboxes);
    k_mask<<<dim3(16, 64, NCLS), dim3(256), 0, stream>>>(sboxes, mask, diag);
    k_nms<<<dim3(NCLS), dim3(256), 0, stream>>>(sscores, order, mask, diag, kept);
    k_topk_final<<<dim3(1), dim3(1024), 0, stream>>>(kept, out);
}